// Round 11
// baseline (519.464 us; speedup 1.0000x reference)
//
#include <hip/hip_runtime.h>
#include <cstdint>
#include <cstddef>

#define TT 1000
#define NB 64000  // B*T

// ---------------------------------------------------------------------------
// NUMERICS CONTRACT (r1/r5/r6/r8/r9/r10 verified absmax 0.0): each z[n,o] is
// ONE ascending-k fp32 fmaf chain. Do not reorder, split, or tree-reduce.
// ---------------------------------------------------------------------------

// async global->LDS DMA: 16B/lane; LDS dest = wave-uniform base + lane*16;
// global src per-lane (base + lane*16B).
__device__ __forceinline__ void dma16(const void* g, void* l) {
  __builtin_amdgcn_global_load_lds(
      (const __attribute__((address_space(1))) unsigned int*)g,
      (__attribute__((address_space(3))) unsigned int*)l, 16, 0, 0);
}

// ---------------------------------------------------------------------------
// Global images (DMA-ready):
//  A: u32 idx = (n>>8)*KT*1024 + kt*1024 + kq*256 + (n&255); byte = k&3,
//     kq = (k>>2)&3   (one k-tile = 1024 dwords = 4KB contiguous)
//  W: f32 idx = ot*KT*2048 + kt*2048 + (k&15)*128 + (o&127)  (8KB per tile)
// ---------------------------------------------------------------------------

// ---------------------------------------------------------------------------
// gemm_bt: Z[n,o] = sum_k W[o,k]*S[n,k].  256n x 128o block, BK=16, 256 thr,
// ASYMMETRIC 16n x 8o thread tile (128 acc): A-side LDS is u8-packed (cheap)
// so widening n-rows cuts LDS bytes/FLOP ~1.7x vs 8x8 -> VALU-bound (r10
// post-mortem: all 8x8 variants were LDS-read-BW-bound at ~85 B/cyc/CU).
// Double-buffered LDS, one barrier/tile, zero-VGPR DMA staging (r9).
// ---------------------------------------------------------------------------
__global__ __launch_bounds__(256) void gemm_bt(
    const unsigned int* __restrict__ Aswz, const float* __restrict__ Wswz,
    float* __restrict__ Z, int KT, int Zld, int Ostore) {
  __shared__ unsigned int Al[2][1024];        // A: [kq][row256] packed u8
  __shared__ __align__(16) float Bl[2][2048]; // B: [k16][o128]
  const int t = threadIdx.x;
  const int lane = t & 63;
  const int wave = t >> 6;
  const int wn = wave >> 1;  // 0/1: n-half
  const int wo = wave & 1;   // 0/1: o-half
  const int np = lane >> 3;  // 0..7
  const int op = lane & 7;   // 0..7
  const int bn = blockIdx.x * 256;
  const int bo = blockIdx.y * 128;

  const unsigned int* asrc =
      Aswz + (size_t)blockIdx.x * KT * 1024 + wave * 256 + lane * 4;
  const float* wsrc =
      Wswz + (size_t)blockIdx.y * KT * 2048 + wave * 512 + lane * 4;

  float acc[16][8];
#pragma unroll
  for (int r = 0; r < 16; r++)
#pragma unroll
    for (int i = 0; i < 8; i++) acc[r][i] = 0.f;

  // prologue: stage tile 0 (A: 4KB = 4 waves x 1 dma; B: 8KB = 4 waves x 2)
  dma16(asrc, &Al[0][wave * 256]);
  dma16(wsrc, &Bl[0][wave * 512]);
  dma16(wsrc + 256, &Bl[0][wave * 512 + 256]);
  __syncthreads();

  const int arow = wn * 128 + np * 16;
  const int bcol = wo * 64 + op * 8;

  for (int tile = 0; tile < KT; tile++) {
    const int cur = tile & 1, nxt = cur ^ 1;
    if (tile + 1 < KT) {  // zero-VGPR async prefetch; lands during ~4k cyc
      dma16(asrc + (size_t)(tile + 1) * 1024, &Al[nxt][wave * 256]);
      const float* wp = wsrc + (size_t)(tile + 1) * 2048;
      dma16(wp, &Bl[nxt][wave * 512]);
      dma16(wp + 256, &Bl[nxt][wave * 512 + 256]);
    }
    const unsigned int* Ac = Al[cur];
    const float* Bc = Bl[cur];
#pragma unroll
    for (int kq = 0; kq < 4; kq++) {
      uint4 a0 = *(const uint4*)&Ac[kq * 256 + arow];
      uint4 a1 = *(const uint4*)&Ac[kq * 256 + arow + 4];
      uint4 a2 = *(const uint4*)&Ac[kq * 256 + arow + 8];
      uint4 a3 = *(const uint4*)&Ac[kq * 256 + arow + 12];
#pragma unroll
      for (int k2 = 0; k2 < 4; k2++) {
        const int kk = kq * 4 + k2;
        const int sh = k2 * 8;
        float av[16];
        av[0] = (float)((a0.x >> sh) & 0xffu);  // v_cvt_f32_ubyteN
        av[1] = (float)((a0.y >> sh) & 0xffu);
        av[2] = (float)((a0.z >> sh) & 0xffu);
        av[3] = (float)((a0.w >> sh) & 0xffu);
        av[4] = (float)((a1.x >> sh) & 0xffu);
        av[5] = (float)((a1.y >> sh) & 0xffu);
        av[6] = (float)((a1.z >> sh) & 0xffu);
        av[7] = (float)((a1.w >> sh) & 0xffu);
        av[8] = (float)((a2.x >> sh) & 0xffu);
        av[9] = (float)((a2.y >> sh) & 0xffu);
        av[10] = (float)((a2.z >> sh) & 0xffu);
        av[11] = (float)((a2.w >> sh) & 0xffu);
        av[12] = (float)((a3.x >> sh) & 0xffu);
        av[13] = (float)((a3.y >> sh) & 0xffu);
        av[14] = (float)((a3.z >> sh) & 0xffu);
        av[15] = (float)((a3.w >> sh) & 0xffu);
        float4 b0 = *(const float4*)&Bc[kk * 128 + bcol];
        float4 b1 = *(const float4*)&Bc[kk * 128 + bcol + 4];
        float bv[8] = {b0.x, b0.y, b0.z, b0.w, b1.x, b1.y, b1.z, b1.w};
#pragma unroll
        for (int r = 0; r < 16; r++)
#pragma unroll
          for (int i = 0; i < 8; i++)
            acc[r][i] = fmaf(av[r], bv[i], acc[r][i]);
      }
    }
    __syncthreads();
  }

  // store 16 rows x 8 cols (o guarded vs Ostore)
  const int o0 = bo + bcol;
#pragma unroll
  for (int r = 0; r < 16; r++) {
    int n = bn + arow + r;
    float* zp = Z + (size_t)n * Zld + o0;
    if (o0 + 7 < Ostore) {
      *(float4*)zp = make_float4(acc[r][0], acc[r][1], acc[r][2], acc[r][3]);
      *(float4*)(zp + 4) =
          make_float4(acc[r][4], acc[r][5], acc[r][6], acc[r][7]);
    } else {
#pragma unroll
      for (int q = 0; q < 8; q++)
        if (o0 + q < Ostore) zp[q] = acc[r][q];
    }
  }
}

// ---------------------------------------------------------------------------
// CUBA LIF recurrence: depth-4 x U=25 load pipeline. Exact per-step fp32
// mul/add chain. Mid layers write u8 spikes into the A image (KT=16):
// byte = (n>>8)*65536 + kof + (n&255)*4, kof = (k>>4)*4096+((k>>2)&3)*1024+(k&3)
// ---------------------------------------------------------------------------
template <bool FINAL>
__global__ __launch_bounds__(64) void cuba_kernel(
    const float* __restrict__ Z, uint8_t* __restrict__ Sout,
    float* __restrict__ Fout, unsigned int* __restrict__ cnt, int O,
    int total) {
  int gid = blockIdx.x * 64 + threadIdx.x;
  unsigned int c = 0;
  if (gid < total) {
    int b = gid / O;
    int o = gid - b * O;
    const int nb = b * TT;
    const float* zp = Z + (size_t)nb * O + o;
    float* fp = Fout + ((size_t)b * O + o) * TT;
    const int kof = (o >> 4) * 4096 + ((o >> 2) & 3) * 1024 + (o & 3);
    float cur = 0.f, volt = 0.f;
    constexpr int U = 25;
    float z0[U], z1[U], z2[U], z3[U];

#define LOADB(buf, tbase)                         \
  _Pragma("unroll") for (int u = 0; u < U; u++) { \
    buf[u] = zp[(size_t)((tbase) + u) * O];       \
  }
#define COMPB(buf, tbase)                                              \
  _Pragma("unroll") for (int u = 0; u < U; u++) {                      \
    cur = __fadd_rn(__fmul_rn(0.75f, cur), buf[u]);                    \
    volt = __fadd_rn(__fmul_rn(0.97f, volt), cur);                     \
    bool fire = volt >= 1.25f;                                         \
    volt = fire ? 0.f : volt;                                          \
    c += fire ? 1u : 0u;                                               \
    if (FINAL) {                                                       \
      fp[(tbase) + u] = fire ? 1.f : 0.f;                              \
    } else {                                                           \
      int n = nb + (tbase) + u;                                        \
      Sout[(size_t)(n >> 8) * 65536 + kof + ((n & 255) << 2)] =        \
          (uint8_t)(fire ? 1 : 0);                                     \
    }                                                                  \
  }

    LOADB(z0, 0)
    LOADB(z1, U)
    LOADB(z2, 2 * U)
    for (int i = 0; i < 10; i++) {
      const int base = i * 4 * U;
      LOADB(z3, base + 3 * U)
      COMPB(z0, base)
      if (i < 9) LOADB(z0, base + 4 * U)
      COMPB(z1, base + U)
      if (i < 9) LOADB(z1, base + 5 * U)
      COMPB(z2, base + 2 * U)
      if (i < 9) LOADB(z2, base + 6 * U)
      COMPB(z3, base + 3 * U)
    }
#undef LOADB
#undef COMPB
  }
#pragma unroll
  for (int off = 32; off; off >>= 1) c += __shfl_down(c, off, 64);
  if ((threadIdx.x & 63) == 0) atomicAdd(cnt, c);
}

// ---------------------------------------------------------------------------
// Fused prep: cnt zero + input image (KT=2) + 4 weight images.
// ---------------------------------------------------------------------------
__device__ __forceinline__ void prep_w_item(const float* __restrict__ W,
                                            float* __restrict__ Wsw, int O,
                                            int K, int KT, int i) {
  int o = i & 127;
  int k16 = (i >> 7) & 15;
  int tile = i >> 11;
  int kt = tile % KT;
  int ot = tile / KT;
  int k = kt * 16 + k16;
  int og = ot * 128 + o;
  Wsw[i] = (k < K && og < O) ? W[(size_t)og * K + k] : 0.f;
}

__global__ __launch_bounds__(256) void prep_all(
    const float* __restrict__ X, const float* __restrict__ W1,
    const float* __restrict__ W2, const float* __restrict__ W3,
    const float* __restrict__ W4, unsigned int* __restrict__ Ain,
    float* __restrict__ Ws1, float* __restrict__ Ws2,
    float* __restrict__ Ws3, float* __restrict__ Ws4,
    unsigned int* __restrict__ cnt) {
  const int blk = blockIdx.x;
  const int tid = threadIdx.x;
  if (blk == 0 && tid < 8) cnt[tid] = 0u;
  if (blk < 250) {
    int gid = blk * 256 + tid;  // n
    unsigned int w[8];
#pragma unroll
    for (int i = 0; i < 8; i++) w[i] = 0u;
#pragma unroll
    for (int c = 0; c < 20; c++) {
      float v = X[((size_t)(gid / TT) * 20 + c) * TT + (gid % TT)];
      w[c >> 2] |= (v != 0.f ? 1u : 0u) << ((c & 3) * 8);
    }
    // A image, KT=2: idx = (n>>8)*2048 + kt*1024 + kq*256 + (n&255)
    unsigned int base = (gid >> 8) * 2048 + (gid & 255);
#pragma unroll
    for (int kd8 = 0; kd8 < 8; kd8++)
      Ain[base + (kd8 >> 2) * 1024 + (kd8 & 3) * 256] = w[kd8];
  } else if (blk < 282) {
    prep_w_item(W1, Ws1, 256, 20, 2, (blk - 250) * 256 + tid);  // 8192
  } else if (blk < 538) {
    prep_w_item(W2, Ws2, 256, 256, 16, (blk - 282) * 256 + tid);  // 65536
  } else if (blk < 794) {
    prep_w_item(W3, Ws3, 256, 256, 16, (blk - 538) * 256 + tid);  // 65536
  } else {
    prep_w_item(W4, Ws4, 35, 256, 16, (blk - 794) * 256 + tid);  // 32768
  }
}

__global__ void finalize_counts(const unsigned int* __restrict__ cnt,
                                float* __restrict__ out) {
  int i = threadIdx.x;
  if (i < 4) {
    const float denom[4] = {16384000.f, 16384000.f, 16384000.f, 2240000.f};
    out[i] = (float)cnt[i] / denom[i];
  }
}

// ---------------------------------------------------------------------------
extern "C" void kernel_launch(void* const* d_in, const int* in_sizes, int n_in,
                              void* d_out, int out_size, void* d_ws,
                              size_t ws_size, hipStream_t stream) {
  const float* X = (const float*)d_in[0];
  const float* W1 = (const float*)d_in[1];
  const float* W2 = (const float*)d_in[2];
  const float* W3 = (const float*)d_in[3];
  const float* W4 = (const float*)d_in[4];
  float* out = (float*)d_out;

  char* ws = (char*)d_ws;
  unsigned int* cnt = (unsigned int*)ws;                       // 256 B
  float* Z = (float*)(ws + 256);                               // 65,536,000
  unsigned int* Sa = (unsigned int*)(ws + 256 + 65536000ull);  // 16,384,000
  unsigned int* Sb = Sa + 4096000ull;                          // 16,384,000
  unsigned int* Sin = Sb + 4096000ull;                         // 2,048,000
  float* Ws1 = (float*)(Sin + 512000ull);                      // 8192 f
  float* Ws2 = Ws1 + 8192;                                     // 65536 f
  float* Ws3 = Ws2 + 65536;                                    // 65536 f
  float* Ws4 = Ws3 + 65536;                                    // 32768 f

  prep_all<<<922, 256, 0, stream>>>(X, W1, W2, W3, W4, Sin, Ws1, Ws2, Ws3,
                                    Ws4, cnt);

  dim3 gBig(250, 2);  // 256n x 128o tiles
  dim3 gOut(250, 1);

  gemm_bt<<<gBig, 256, 0, stream>>>(Sin, Ws1, Z, 2, 256, 256);
  cuba_kernel<false><<<256, 64, 0, stream>>>(Z, (uint8_t*)Sa, nullptr, cnt + 0,
                                             256, 16384);
  gemm_bt<<<gBig, 256, 0, stream>>>(Sa, Ws2, Z, 16, 256, 256);
  cuba_kernel<false><<<256, 64, 0, stream>>>(Z, (uint8_t*)Sb, nullptr, cnt + 1,
                                             256, 16384);
  gemm_bt<<<gBig, 256, 0, stream>>>(Sb, Ws3, Z, 16, 256, 256);
  cuba_kernel<false><<<256, 64, 0, stream>>>(Z, (uint8_t*)Sa, nullptr, cnt + 2,
                                             256, 16384);
  gemm_bt<<<gOut, 256, 0, stream>>>(Sa, Ws4, Z, 16, 35, 35);
  cuba_kernel<true><<<35, 64, 0, stream>>>(Z, nullptr, out, cnt + 3, 35, 2240);
  finalize_counts<<<1, 64, 0, stream>>>(cnt, out + 2240000);
}

// Round 12
// 481.314 us; speedup vs baseline: 1.0793x; 1.0793x over previous
//
#include <hip/hip_runtime.h>
#include <cstdint>
#include <cstddef>

#define TT 1000
#define NB 64000  // B*T

// ---------------------------------------------------------------------------
// NUMERICS CONTRACT (r1/r5/r6/r8-r11 verified absmax 0.0): each z[n,o] is
// ONE ascending-k fp32 fmaf chain. Do not reorder, split, or tree-reduce.
// ---------------------------------------------------------------------------

// async global->LDS DMA: 16B/lane; LDS dest = wave-uniform base + lane*16;
// global src per-lane.
__device__ __forceinline__ void dma16(const void* g, void* l) {
  __builtin_amdgcn_global_load_lds(
      (const __attribute__((address_space(1))) unsigned int*)g,
      (__attribute__((address_space(3))) unsigned int*)l, 16, 0, 0);
}

// ---------------------------------------------------------------------------
// A image (DMA-ready): u32 idx = (n>>7)*KT*512 + kt*512 + kd*128 + (n&127);
// byte = k&3, kd = (k>>2)&3. One k-tile (128 rows x 16 k) = 2 KB contiguous.
// W: plain transposed [K][Opad] f32.
// ---------------------------------------------------------------------------

// ---------------------------------------------------------------------------
// gemm_dma (r9, best measured 108 us): 128n x 128o, BK=16, 256 thr, 8x8.
// Double-buffered LDS, one barrier/tile, zero-VGPR DMA staging.
// ---------------------------------------------------------------------------
__global__ __launch_bounds__(256) void gemm_dma(
    const unsigned int* __restrict__ Aswz, const float* __restrict__ Wt,
    float* __restrict__ Z, int KT, int Wld, int Zld, int Ostore) {
  __shared__ unsigned int AsU[2][512];
  __shared__ __align__(16) float Bs[2][2048];
  const int t = threadIdx.x;
  const int lane = t & 63;
  const int wave = t >> 6;
  const int bn = blockIdx.x * 128;
  const int bo = blockIdx.y * 128;
  const int tx4 = (t & 15) * 4;
  const int ty4 = ((t >> 4) & 15) * 4;

  const int f0 = wave * 64 + lane;
  const int bk0 = f0 >> 5;
  const int bc0 = (f0 & 31) * 4;
  const float* wsrc = Wt + (size_t)bk0 * Wld + bo + bc0;
  const unsigned int* asrc =
      Aswz + (size_t)blockIdx.x * KT * 512 + wave * 256 + lane * 4;

  float acc[8][8];
#pragma unroll
  for (int j = 0; j < 8; j++)
#pragma unroll
    for (int i = 0; i < 8; i++) acc[j][i] = 0.f;

  dma16(wsrc, &Bs[0][wave * 256]);
  dma16(wsrc + (size_t)8 * Wld, &Bs[0][1024 + wave * 256]);
  if (wave < 2) dma16(asrc, &AsU[0][wave * 256]);
  __syncthreads();

  for (int tile = 0; tile < KT; tile++) {
    const int cur = tile & 1, nxt = cur ^ 1;
    if (tile + 1 < KT) {
      const float* wn = wsrc + (size_t)(tile + 1) * 16 * Wld;
      dma16(wn, &Bs[nxt][wave * 256]);
      dma16(wn + (size_t)8 * Wld, &Bs[nxt][1024 + wave * 256]);
      if (wave < 2)
        dma16(asrc + (size_t)(tile + 1) * 512, &AsU[nxt][wave * 256]);
    }
#pragma unroll
    for (int kq = 0; kq < 4; kq++) {
      uint4 a0 = *(const uint4*)&AsU[cur][kq * 128 + ty4];
      uint4 a1 = *(const uint4*)&AsU[cur][kq * 128 + 64 + ty4];
#pragma unroll
      for (int k2 = 0; k2 < 4; k2++) {
        const int kk = kq * 4 + k2;
        const int sh = k2 * 8;
        float av[8];
        av[0] = (float)((a0.x >> sh) & 0xffu);
        av[1] = (float)((a0.y >> sh) & 0xffu);
        av[2] = (float)((a0.z >> sh) & 0xffu);
        av[3] = (float)((a0.w >> sh) & 0xffu);
        av[4] = (float)((a1.x >> sh) & 0xffu);
        av[5] = (float)((a1.y >> sh) & 0xffu);
        av[6] = (float)((a1.z >> sh) & 0xffu);
        av[7] = (float)((a1.w >> sh) & 0xffu);
        float4 b0 = *(const float4*)&Bs[cur][kk * 128 + tx4];
        float4 b1 = *(const float4*)&Bs[cur][kk * 128 + 64 + tx4];
        float bv[8] = {b0.x, b0.y, b0.z, b0.w, b1.x, b1.y, b1.z, b1.w};
#pragma unroll
        for (int j = 0; j < 8; j++)
#pragma unroll
          for (int i = 0; i < 8; i++)
            acc[j][i] = fmaf(av[j], bv[i], acc[j][i]);
      }
    }
    __syncthreads();
  }

#pragma unroll
  for (int jp = 0; jp < 2; jp++) {
#pragma unroll
    for (int j = 0; j < 4; j++) {
      int n = bn + jp * 64 + ty4 + j;
#pragma unroll
      for (int ip = 0; ip < 2; ip++) {
        int o0 = bo + ip * 64 + tx4;
        const float* a = &acc[jp * 4 + j][ip * 4];
        float* zp = Z + (size_t)n * Zld + o0;
        if (o0 + 3 < Ostore) {
          *(float4*)zp = make_float4(a[0], a[1], a[2], a[3]);
        } else {
#pragma unroll
          for (int q = 0; q < 4; q++)
            if (o0 + q < Ostore) zp[q] = a[q];
        }
      }
    }
  }
}

// ---------------------------------------------------------------------------
// gemm_l4: layer 4 (O=35, padded 64). 256n x 64o block, 250 blocks (1/CU),
// K=256 (KT=16). Waves split n 4-ways (64n x 64o each); lane 8n x 8o.
// A: r9 image, two 128-row tiles per block. Wt4: [256][64] transposed.
// No wasted o-columns (r9 computed 128 wide for 35 stored).
// ---------------------------------------------------------------------------
__global__ __launch_bounds__(256) void gemm_l4(
    const unsigned int* __restrict__ Aswz, const float* __restrict__ Wt,
    float* __restrict__ Z) {
  const int KT = 16, OS = 35;
  __shared__ unsigned int Al[2][1024];        // 2 tiles x 512 dwords
  __shared__ __align__(16) float Bl[2][1024]; // 16k x 64o
  const int t = threadIdx.x;
  const int lane = t & 63;
  const int wave = t >> 6;
  const int bn = blockIdx.x * 256;
  const int h = wave >> 1;  // which 128-row A tile
  const int ny = (lane >> 3) * 8;
  const int ox = (lane & 7) * 8;
  const int lrow = (wave & 1) * 64 + ny;  // row within 128-tile

  // A staging: waves 0,1 -> tile0; waves 2,3 -> tile1 (each 256 dwords)
  const unsigned int* asrc = Aswz +
      (size_t)(blockIdx.x * 2 + (wave >> 1)) * KT * 512 + (wave & 1) * 256 +
      lane * 4;
  // B staging: 4 waves x 256 floats (16x64 tile contiguous, Wld=64)
  const float* wsrc = Wt + wave * 256 + lane * 4;

  float acc[8][8];
#pragma unroll
  for (int j = 0; j < 8; j++)
#pragma unroll
    for (int i = 0; i < 8; i++) acc[j][i] = 0.f;

  dma16(asrc, &Al[0][wave * 256]);
  dma16(wsrc, &Bl[0][wave * 256]);
  __syncthreads();

  for (int tile = 0; tile < KT; tile++) {
    const int cur = tile & 1, nxt = cur ^ 1;
    if (tile + 1 < KT) {
      dma16(asrc + (size_t)(tile + 1) * 512, &Al[nxt][wave * 256]);
      dma16(wsrc + (size_t)(tile + 1) * 1024, &Bl[nxt][wave * 256]);
    }
#pragma unroll
    for (int kq = 0; kq < 4; kq++) {
      uint4 a0 = *(const uint4*)&Al[cur][h * 512 + kq * 128 + lrow];
      uint4 a1 = *(const uint4*)&Al[cur][h * 512 + kq * 128 + lrow + 4];
#pragma unroll
      for (int k2 = 0; k2 < 4; k2++) {
        const int kk = kq * 4 + k2;
        const int sh = k2 * 8;
        float av[8];
        av[0] = (float)((a0.x >> sh) & 0xffu);
        av[1] = (float)((a0.y >> sh) & 0xffu);
        av[2] = (float)((a0.z >> sh) & 0xffu);
        av[3] = (float)((a0.w >> sh) & 0xffu);
        av[4] = (float)((a1.x >> sh) & 0xffu);
        av[5] = (float)((a1.y >> sh) & 0xffu);
        av[6] = (float)((a1.z >> sh) & 0xffu);
        av[7] = (float)((a1.w >> sh) & 0xffu);
        float4 b0 = *(const float4*)&Bl[cur][kk * 64 + ox];
        float4 b1 = *(const float4*)&Bl[cur][kk * 64 + ox + 4];
        float bv[8] = {b0.x, b0.y, b0.z, b0.w, b1.x, b1.y, b1.z, b1.w};
#pragma unroll
        for (int j = 0; j < 8; j++)
#pragma unroll
          for (int i = 0; i < 8; i++)
            acc[j][i] = fmaf(av[j], bv[i], acc[j][i]);
      }
    }
    __syncthreads();
  }

  // store rows bn + wave*64 + ny + j, cols ox.. (guard o < 35), Z stride 35
#pragma unroll
  for (int j = 0; j < 8; j++) {
    int n = bn + wave * 64 + ny + j;
    float* zp = Z + (size_t)n * OS + ox;
    if (ox + 7 < OS) {
      *(float4*)zp = make_float4(acc[j][0], acc[j][1], acc[j][2], acc[j][3]);
      *(float4*)(zp + 4) =
          make_float4(acc[j][4], acc[j][5], acc[j][6], acc[j][7]);
    } else {
#pragma unroll
      for (int q = 0; q < 8; q++)
        if (ox + q < OS) zp[q] = acc[j][q];
    }
  }
}

// ---------------------------------------------------------------------------
// CUBA LIF recurrence. Depth-2 x U=25 pipeline: max 50 outstanding vmem
// instructions per wave (<= vmcnt cap 63; the old depth-4x25=100 exceeded
// it and serialized). Exact per-step fp32 mul/add chain (order unchanged).
// Mid layers write u8 spikes into the A image (KT=16).
// ---------------------------------------------------------------------------
template <bool FINAL>
__global__ __launch_bounds__(64) void cuba_kernel(
    const float* __restrict__ Z, uint8_t* __restrict__ Sout,
    float* __restrict__ Fout, unsigned int* __restrict__ cnt, int O,
    int total) {
  int gid = blockIdx.x * 64 + threadIdx.x;
  unsigned int c = 0;
  if (gid < total) {
    int b = gid / O;
    int o = gid - b * O;
    const int nb = b * TT;
    const float* zp = Z + (size_t)nb * O + o;
    float* fp = Fout + ((size_t)b * O + o) * TT;
    const int koff = (o >> 4) * 2048 + ((o >> 2) & 3) * 512 + (o & 3);
    float cur = 0.f, volt = 0.f;
    constexpr int U = 25;  // 1000 = 40 batches, 2-deep pipeline
    float z0[U], z1[U];

#define LOADB(buf, tbase)                         \
  _Pragma("unroll") for (int u = 0; u < U; u++) { \
    buf[u] = zp[(size_t)((tbase) + u) * O];       \
  }
#define COMPB(buf, tbase)                                              \
  _Pragma("unroll") for (int u = 0; u < U; u++) {                      \
    cur = __fadd_rn(__fmul_rn(0.75f, cur), buf[u]);                    \
    volt = __fadd_rn(__fmul_rn(0.97f, volt), cur);                     \
    bool fire = volt >= 1.25f;                                         \
    volt = fire ? 0.f : volt;                                          \
    c += fire ? 1u : 0u;                                               \
    if (FINAL) {                                                       \
      fp[(tbase) + u] = fire ? 1.f : 0.f;                              \
    } else {                                                           \
      int n = nb + (tbase) + u;                                        \
      Sout[(size_t)(n >> 7) * 32768 + koff + ((n & 127) << 2)] =       \
          (uint8_t)(fire ? 1 : 0);                                     \
    }                                                                  \
  }

    LOADB(z0, 0)
    for (int i = 0; i < 20; i++) {
      const int base = i * 2 * U;
      LOADB(z1, base + U)
      COMPB(z0, base)
      if (i < 19) LOADB(z0, base + 2 * U)
      COMPB(z1, base + U)
    }
#undef LOADB
#undef COMPB
  }
#pragma unroll
  for (int off = 32; off; off >>= 1) c += __shfl_down(c, off, 64);
  if ((threadIdx.x & 63) == 0) atomicAdd(cnt, c);
}

// ---------------------------------------------------------------------------
// Fused prep: cnt zero + input image (KT=2) + 4 weight transposes.
// ---------------------------------------------------------------------------
__device__ __forceinline__ void prep_w_item(const float* __restrict__ W,
                                            float* __restrict__ Wt, int O,
                                            int K, int Opad, int i) {
  int k = i / Opad, o = i - k * Opad;
  Wt[i] = (k < K && o < O) ? W[(size_t)o * K + k] : 0.f;
}

__global__ __launch_bounds__(256) void prep_all(
    const float* __restrict__ X, const float* __restrict__ W1,
    const float* __restrict__ W2, const float* __restrict__ W3,
    const float* __restrict__ W4, unsigned int* __restrict__ Ain,
    float* __restrict__ Wt1, float* __restrict__ Wt2,
    float* __restrict__ Wt3, float* __restrict__ Wt4,
    unsigned int* __restrict__ cnt) {
  const int blk = blockIdx.x;
  const int tid = threadIdx.x;
  if (blk == 0 && tid < 8) cnt[tid] = 0u;
  if (blk < 250) {
    int gid = blk * 256 + tid;  // n
    unsigned int w[8];
#pragma unroll
    for (int i = 0; i < 8; i++) w[i] = 0u;
#pragma unroll
    for (int c = 0; c < 20; c++) {
      float v = X[((size_t)(gid / TT) * 20 + c) * TT + (gid % TT)];
      w[c >> 2] |= (v != 0.f ? 1u : 0u) << ((c & 3) * 8);
    }
    // A image, KT=2: idx = (n>>7)*1024 + kt*512 + kd*128 + (n&127)
    unsigned int base = (gid >> 7) * 1024 + (gid & 127);
#pragma unroll
    for (int kd8 = 0; kd8 < 8; kd8++)
      Ain[base + (kd8 >> 2) * 512 + (kd8 & 3) * 128] = w[kd8];
  } else if (blk < 282) {
    prep_w_item(W1, Wt1, 256, 20, 256, (blk - 250) * 256 + tid);  // 8192
  } else if (blk < 538) {
    prep_w_item(W2, Wt2, 256, 256, 256, (blk - 282) * 256 + tid);  // 65536
  } else if (blk < 794) {
    prep_w_item(W3, Wt3, 256, 256, 256, (blk - 538) * 256 + tid);  // 65536
  } else {
    prep_w_item(W4, Wt4, 35, 256, 64, (blk - 794) * 256 + tid);  // 16384
  }
}

__global__ void finalize_counts(const unsigned int* __restrict__ cnt,
                                float* __restrict__ out) {
  int i = threadIdx.x;
  if (i < 4) {
    const float denom[4] = {16384000.f, 16384000.f, 16384000.f, 2240000.f};
    out[i] = (float)cnt[i] / denom[i];
  }
}

// ---------------------------------------------------------------------------
extern "C" void kernel_launch(void* const* d_in, const int* in_sizes, int n_in,
                              void* d_out, int out_size, void* d_ws,
                              size_t ws_size, hipStream_t stream) {
  const float* X = (const float*)d_in[0];
  const float* W1 = (const float*)d_in[1];
  const float* W2 = (const float*)d_in[2];
  const float* W3 = (const float*)d_in[3];
  const float* W4 = (const float*)d_in[4];
  float* out = (float*)d_out;

  char* ws = (char*)d_ws;
  unsigned int* cnt = (unsigned int*)ws;                       // 256 B
  float* Z = (float*)(ws + 256);                               // 65,536,000
  unsigned int* Sa = (unsigned int*)(ws + 256 + 65536000ull);  // 16,384,000
  unsigned int* Sb = Sa + 4096000ull;                          // 16,384,000
  unsigned int* Sin = Sb + 4096000ull;                         // 2,048,000
  float* Wt1 = (float*)(Sin + 512000ull);                      // 8192 f
  float* Wt2 = Wt1 + 8192;                                     // 65536 f
  float* Wt3 = Wt2 + 65536;                                    // 65536 f
  float* Wt4 = Wt3 + 65536;                                    // 16384 f

  prep_all<<<858, 256, 0, stream>>>(X, W1, W2, W3, W4, Sin, Wt1, Wt2, Wt3,
                                    Wt4, cnt);

  dim3 gBig(500, 2);

  gemm_dma<<<gBig, 256, 0, stream>>>(Sin, Wt1, Z, 2, 256, 256, 256);
  cuba_kernel<false><<<256, 64, 0, stream>>>(Z, (uint8_t*)Sa, nullptr, cnt + 0,
                                             256, 16384);
  gemm_dma<<<gBig, 256, 0, stream>>>(Sa, Wt2, Z, 16, 256, 256, 256);
  cuba_kernel<false><<<256, 64, 0, stream>>>(Z, (uint8_t*)Sb, nullptr, cnt + 1,
                                             256, 16384);
  gemm_dma<<<gBig, 256, 0, stream>>>(Sb, Wt3, Z, 16, 256, 256, 256);
  cuba_kernel<false><<<256, 64, 0, stream>>>(Z, (uint8_t*)Sa, nullptr, cnt + 2,
                                             256, 16384);
  gemm_l4<<<250, 256, 0, stream>>>(Sa, Wt4, Z);
  cuba_kernel<true><<<35, 64, 0, stream>>>(Z, nullptr, out, cnt + 3, 35, 2240);
  finalize_counts<<<1, 64, 0, stream>>>(cnt, out + 2240000);
}

// Round 13
// 475.534 us; speedup vs baseline: 1.0924x; 1.0122x over previous
//
#include <hip/hip_runtime.h>
#include <cstdint>
#include <cstddef>

#define TT 1000
#define NB 64000  // B*T

// ---------------------------------------------------------------------------
// NUMERICS CONTRACT (r1/r5/r6/r8-r12 verified absmax 0.0): each z[n,o] is
// ONE ascending-k fp32 fmaf chain. Do not reorder, split, or tree-reduce.
// (r4's value-exact 3-way bf16 split FAILED on summation order alone —
// reordering provably flips spikes. Order is sacred.)
// ---------------------------------------------------------------------------

// async global->LDS DMA: 16B/lane; LDS dest = wave-uniform base + lane*16;
// global src per-lane.
__device__ __forceinline__ void dma16(const void* g, void* l) {
  __builtin_amdgcn_global_load_lds(
      (const __attribute__((address_space(1))) unsigned int*)g,
      (__attribute__((address_space(3))) unsigned int*)l, 16, 0, 0);
}

// ---------------------------------------------------------------------------
// A image (DMA-ready): u32 idx = (n>>7)*(K/16)*512 + kt16*512 + kd*128
//   + (n&127); byte = k&3, kd = (k>>2)&3.  16-k chunks are contiguous, so a
//   BK=32 tile = 1024 contiguous dwords (two 512 halves).
// W: plain transposed [K][Opad] f32.
// ---------------------------------------------------------------------------

// ---------------------------------------------------------------------------
// gemm_dma BK=32: 128n x 128o block, 256 thr, 8x8/thread. Double-buffered
// LDS (40 KB), ONE barrier per 32-k tile (half the drain events of r9/r12's
// BK=16 — the measured ~15% idle is barrier-drain at ~2 blocks/CU).
// Zero-VGPR global_load_lds staging for both A (u8-packed) and B.
// ---------------------------------------------------------------------------
__global__ __launch_bounds__(256) void gemm_dma(
    const unsigned int* __restrict__ Aswz, const float* __restrict__ Wt,
    float* __restrict__ Z, int KT32, int Wld, int Zld, int Ostore) {
  __shared__ unsigned int AsU[2][1024];        // 32k x 128row packed u8
  __shared__ __align__(16) float Bs[2][4096];  // 32k x 128o
  const int t = threadIdx.x;
  const int lane = t & 63;
  const int wave = t >> 6;
  const int bn = blockIdx.x * 128;
  const int bo = blockIdx.y * 128;
  const int tx4 = (t & 15) * 4;
  const int ty4 = ((t >> 4) & 15) * 4;

  // B DMA geometry: wave covers rows 2w..2w+1 (+8d per dma d)
  const int f0 = wave * 64 + lane;
  const int bk0 = f0 >> 5;
  const int bc0 = (f0 & 31) * 4;
  const float* wsrc = Wt + (size_t)bk0 * Wld + bo + bc0;
  // A DMA: 4 waves x 256 dwords = 1024 dwords (one 32-k tile)
  const unsigned int* asrc =
      Aswz + (size_t)blockIdx.x * KT32 * 1024 + wave * 256 + lane * 4;

  float acc[8][8];
#pragma unroll
  for (int j = 0; j < 8; j++)
#pragma unroll
    for (int i = 0; i < 8; i++) acc[j][i] = 0.f;

  // prologue: stage tile 0
#pragma unroll
  for (int d = 0; d < 4; d++)
    dma16(wsrc + (size_t)(8 * d) * Wld, &Bs[0][1024 * d + wave * 256]);
  dma16(asrc, &AsU[0][wave * 256]);
  __syncthreads();

  for (int tile = 0; tile < KT32; tile++) {
    const int cur = tile & 1, nxt = cur ^ 1;
    if (tile + 1 < KT32) {  // zero-VGPR async prefetch, lands during compute
      const float* wn = wsrc + (size_t)(tile + 1) * 32 * Wld;
#pragma unroll
      for (int d = 0; d < 4; d++)
        dma16(wn + (size_t)(8 * d) * Wld, &Bs[nxt][1024 * d + wave * 256]);
      dma16(asrc + (size_t)(tile + 1) * 1024, &AsU[nxt][wave * 256]);
    }
#pragma unroll
    for (int kh = 0; kh < 2; kh++) {
#pragma unroll
      for (int kq = 0; kq < 4; kq++) {
        uint4 a0 = *(const uint4*)&AsU[cur][kh * 512 + kq * 128 + ty4];
        uint4 a1 = *(const uint4*)&AsU[cur][kh * 512 + kq * 128 + 64 + ty4];
#pragma unroll
        for (int k2 = 0; k2 < 4; k2++) {
          const int kk = kh * 16 + kq * 4 + k2;
          const int sh = k2 * 8;
          float av[8];
          av[0] = (float)((a0.x >> sh) & 0xffu);  // v_cvt_f32_ubyte
          av[1] = (float)((a0.y >> sh) & 0xffu);
          av[2] = (float)((a0.z >> sh) & 0xffu);
          av[3] = (float)((a0.w >> sh) & 0xffu);
          av[4] = (float)((a1.x >> sh) & 0xffu);
          av[5] = (float)((a1.y >> sh) & 0xffu);
          av[6] = (float)((a1.z >> sh) & 0xffu);
          av[7] = (float)((a1.w >> sh) & 0xffu);
          float4 b0 = *(const float4*)&Bs[cur][kk * 128 + tx4];
          float4 b1 = *(const float4*)&Bs[cur][kk * 128 + 64 + tx4];
          float bv[8] = {b0.x, b0.y, b0.z, b0.w, b1.x, b1.y, b1.z, b1.w};
#pragma unroll
          for (int j = 0; j < 8; j++)
#pragma unroll
            for (int i = 0; i < 8; i++)
              acc[j][i] = fmaf(av[j], bv[i], acc[j][i]);
        }
      }
    }
    __syncthreads();
  }

#pragma unroll
  for (int jp = 0; jp < 2; jp++) {
#pragma unroll
    for (int j = 0; j < 4; j++) {
      int n = bn + jp * 64 + ty4 + j;
#pragma unroll
      for (int ip = 0; ip < 2; ip++) {
        int o0 = bo + ip * 64 + tx4;
        const float* a = &acc[jp * 4 + j][ip * 4];
        float* zp = Z + (size_t)n * Zld + o0;
        if (o0 + 3 < Ostore) {
          *(float4*)zp = make_float4(a[0], a[1], a[2], a[3]);
        } else {
#pragma unroll
          for (int q = 0; q < 4; q++)
            if (o0 + q < Ostore) zp[q] = a[q];
        }
      }
    }
  }
}

// ---------------------------------------------------------------------------
// gemm_l4 (r12, proven): layer 4, O=35 padded 64. 256n x 64o block, BK=16.
// ---------------------------------------------------------------------------
__global__ __launch_bounds__(256) void gemm_l4(
    const unsigned int* __restrict__ Aswz, const float* __restrict__ Wt,
    float* __restrict__ Z) {
  const int KT = 16, OS = 35;
  __shared__ unsigned int Al[2][1024];
  __shared__ __align__(16) float Bl[2][1024];
  const int t = threadIdx.x;
  const int lane = t & 63;
  const int wave = t >> 6;
  const int bn = blockIdx.x * 256;
  const int h = wave >> 1;
  const int ny = (lane >> 3) * 8;
  const int ox = (lane & 7) * 8;
  const int lrow = (wave & 1) * 64 + ny;

  const unsigned int* asrc = Aswz +
      (size_t)(blockIdx.x * 2 + (wave >> 1)) * KT * 512 + (wave & 1) * 256 +
      lane * 4;
  const float* wsrc = Wt + wave * 256 + lane * 4;

  float acc[8][8];
#pragma unroll
  for (int j = 0; j < 8; j++)
#pragma unroll
    for (int i = 0; i < 8; i++) acc[j][i] = 0.f;

  dma16(asrc, &Al[0][wave * 256]);
  dma16(wsrc, &Bl[0][wave * 256]);
  __syncthreads();

  for (int tile = 0; tile < KT; tile++) {
    const int cur = tile & 1, nxt = cur ^ 1;
    if (tile + 1 < KT) {
      dma16(asrc + (size_t)(tile + 1) * 512, &Al[nxt][wave * 256]);
      dma16(wsrc + (size_t)(tile + 1) * 1024, &Bl[nxt][wave * 256]);
    }
#pragma unroll
    for (int kq = 0; kq < 4; kq++) {
      uint4 a0 = *(const uint4*)&Al[cur][h * 512 + kq * 128 + lrow];
      uint4 a1 = *(const uint4*)&Al[cur][h * 512 + kq * 128 + lrow + 4];
#pragma unroll
      for (int k2 = 0; k2 < 4; k2++) {
        const int kk = kq * 4 + k2;
        const int sh = k2 * 8;
        float av[8];
        av[0] = (float)((a0.x >> sh) & 0xffu);
        av[1] = (float)((a0.y >> sh) & 0xffu);
        av[2] = (float)((a0.z >> sh) & 0xffu);
        av[3] = (float)((a0.w >> sh) & 0xffu);
        av[4] = (float)((a1.x >> sh) & 0xffu);
        av[5] = (float)((a1.y >> sh) & 0xffu);
        av[6] = (float)((a1.z >> sh) & 0xffu);
        av[7] = (float)((a1.w >> sh) & 0xffu);
        float4 b0 = *(const float4*)&Bl[cur][kk * 64 + ox];
        float4 b1 = *(const float4*)&Bl[cur][kk * 64 + ox + 4];
        float bv[8] = {b0.x, b0.y, b0.z, b0.w, b1.x, b1.y, b1.z, b1.w};
#pragma unroll
        for (int j = 0; j < 8; j++)
#pragma unroll
          for (int i = 0; i < 8; i++)
            acc[j][i] = fmaf(av[j], bv[i], acc[j][i]);
      }
    }
    __syncthreads();
  }

#pragma unroll
  for (int j = 0; j < 8; j++) {
    int n = bn + wave * 64 + ny + j;
    float* zp = Z + (size_t)n * OS + ox;
    if (ox + 7 < OS) {
      *(float4*)zp = make_float4(acc[j][0], acc[j][1], acc[j][2], acc[j][3]);
      *(float4*)(zp + 4) =
          make_float4(acc[j][4], acc[j][5], acc[j][6], acc[j][7]);
    } else {
#pragma unroll
      for (int q = 0; q < 8; q++)
        if (ox + q < OS) zp[q] = acc[j][q];
    }
  }
}

// ---------------------------------------------------------------------------
// CUBA LIF recurrence (r12): depth-2 x U=25 pipeline (50 outstanding <= 63
// vmcnt cap). Exact per-step fp32 mul/add chain. Mid layers write u8 spikes
// into the A image (16-k chunk granularity).
// ---------------------------------------------------------------------------
template <bool FINAL>
__global__ __launch_bounds__(64) void cuba_kernel(
    const float* __restrict__ Z, uint8_t* __restrict__ Sout,
    float* __restrict__ Fout, unsigned int* __restrict__ cnt, int O,
    int total) {
  int gid = blockIdx.x * 64 + threadIdx.x;
  unsigned int c = 0;
  if (gid < total) {
    int b = gid / O;
    int o = gid - b * O;
    const int nb = b * TT;
    const float* zp = Z + (size_t)nb * O + o;
    float* fp = Fout + ((size_t)b * O + o) * TT;
    const int koff = (o >> 4) * 2048 + ((o >> 2) & 3) * 512 + (o & 3);
    float cur = 0.f, volt = 0.f;
    constexpr int U = 25;
    float z0[U], z1[U];

#define LOADB(buf, tbase)                         \
  _Pragma("unroll") for (int u = 0; u < U; u++) { \
    buf[u] = zp[(size_t)((tbase) + u) * O];       \
  }
#define COMPB(buf, tbase)                                              \
  _Pragma("unroll") for (int u = 0; u < U; u++) {                      \
    cur = __fadd_rn(__fmul_rn(0.75f, cur), buf[u]);                    \
    volt = __fadd_rn(__fmul_rn(0.97f, volt), cur);                     \
    bool fire = volt >= 1.25f;                                         \
    volt = fire ? 0.f : volt;                                          \
    c += fire ? 1u : 0u;                                               \
    if (FINAL) {                                                       \
      fp[(tbase) + u] = fire ? 1.f : 0.f;                              \
    } else {                                                           \
      int n = nb + (tbase) + u;                                        \
      Sout[(size_t)(n >> 7) * 32768 + koff + ((n & 127) << 2)] =       \
          (uint8_t)(fire ? 1 : 0);                                     \
    }                                                                  \
  }

    LOADB(z0, 0)
    for (int i = 0; i < 20; i++) {
      const int base = i * 2 * U;
      LOADB(z1, base + U)
      COMPB(z0, base)
      if (i < 19) LOADB(z0, base + 2 * U)
      COMPB(z1, base + U)
    }
#undef LOADB
#undef COMPB
  }
#pragma unroll
  for (int off = 32; off; off >>= 1) c += __shfl_down(c, off, 64);
  if ((threadIdx.x & 63) == 0) atomicAdd(cnt, c);
}

// ---------------------------------------------------------------------------
// Fused prep: cnt zero + input image + 4 weight transposes. (r12)
// ---------------------------------------------------------------------------
__device__ __forceinline__ void prep_w_item(const float* __restrict__ W,
                                            float* __restrict__ Wt, int O,
                                            int K, int Opad, int i) {
  int k = i / Opad, o = i - k * Opad;
  Wt[i] = (k < K && o < O) ? W[(size_t)o * K + k] : 0.f;
}

__global__ __launch_bounds__(256) void prep_all(
    const float* __restrict__ X, const float* __restrict__ W1,
    const float* __restrict__ W2, const float* __restrict__ W3,
    const float* __restrict__ W4, unsigned int* __restrict__ Ain,
    float* __restrict__ Wt1, float* __restrict__ Wt2,
    float* __restrict__ Wt3, float* __restrict__ Wt4,
    unsigned int* __restrict__ cnt) {
  const int blk = blockIdx.x;
  const int tid = threadIdx.x;
  if (blk == 0 && tid < 8) cnt[tid] = 0u;
  if (blk < 250) {
    int gid = blk * 256 + tid;  // n
    unsigned int w[8];
#pragma unroll
    for (int i = 0; i < 8; i++) w[i] = 0u;
#pragma unroll
    for (int c = 0; c < 20; c++) {
      float v = X[((size_t)(gid / TT) * 20 + c) * TT + (gid % TT)];
      w[c >> 2] |= (v != 0.f ? 1u : 0u) << ((c & 3) * 8);
    }
    // A image (K=32): idx = (n>>7)*1024 + k16*512 + kd*128 + (n&127)
    unsigned int base = (gid >> 7) * 1024 + (gid & 127);
#pragma unroll
    for (int kd8 = 0; kd8 < 8; kd8++)
      Ain[base + (kd8 >> 2) * 512 + (kd8 & 3) * 128] = w[kd8];
  } else if (blk < 282) {
    prep_w_item(W1, Wt1, 256, 20, 256, (blk - 250) * 256 + tid);
  } else if (blk < 538) {
    prep_w_item(W2, Wt2, 256, 256, 256, (blk - 282) * 256 + tid);
  } else if (blk < 794) {
    prep_w_item(W3, Wt3, 256, 256, 256, (blk - 538) * 256 + tid);
  } else {
    prep_w_item(W4, Wt4, 35, 256, 64, (blk - 794) * 256 + tid);
  }
}

__global__ void finalize_counts(const unsigned int* __restrict__ cnt,
                                float* __restrict__ out) {
  int i = threadIdx.x;
  if (i < 4) {
    const float denom[4] = {16384000.f, 16384000.f, 16384000.f, 2240000.f};
    out[i] = (float)cnt[i] / denom[i];
  }
}

// ---------------------------------------------------------------------------
extern "C" void kernel_launch(void* const* d_in, const int* in_sizes, int n_in,
                              void* d_out, int out_size, void* d_ws,
                              size_t ws_size, hipStream_t stream) {
  const float* X = (const float*)d_in[0];
  const float* W1 = (const float*)d_in[1];
  const float* W2 = (const float*)d_in[2];
  const float* W3 = (const float*)d_in[3];
  const float* W4 = (const float*)d_in[4];
  float* out = (float*)d_out;

  char* ws = (char*)d_ws;
  unsigned int* cnt = (unsigned int*)ws;                       // 256 B
  float* Z = (float*)(ws + 256);                               // 65,536,000
  unsigned int* Sa = (unsigned int*)(ws + 256 + 65536000ull);  // 16,384,000
  unsigned int* Sb = Sa + 4096000ull;                          // 16,384,000
  unsigned int* Sin = Sb + 4096000ull;                         // 2,048,000
  float* Wt1 = (float*)(Sin + 512000ull);                      // 8192 f
  float* Wt2 = Wt1 + 8192;                                     // 65536 f
  float* Wt3 = Wt2 + 65536;                                    // 65536 f
  float* Wt4 = Wt3 + 65536;                                    // 16384 f

  prep_all<<<858, 256, 0, stream>>>(X, W1, W2, W3, W4, Sin, Wt1, Wt2, Wt3,
                                    Wt4, cnt);

  dim3 gBig(500, 2);

  gemm_dma<<<gBig, 256, 0, stream>>>(Sin, Wt1, Z, 1, 256, 256, 256);
  cuba_kernel<false><<<256, 64, 0, stream>>>(Z, (uint8_t*)Sa, nullptr, cnt + 0,
                                             256, 16384);
  gemm_dma<<<gBig, 256, 0, stream>>>(Sa, Wt2, Z, 8, 256, 256, 256);
  cuba_kernel<false><<<256, 64, 0, stream>>>(Z, (uint8_t*)Sb, nullptr, cnt + 1,
                                             256, 16384);
  gemm_dma<<<gBig, 256, 0, stream>>>(Sb, Wt3, Z, 8, 256, 256, 256);
  cuba_kernel<false><<<256, 64, 0, stream>>>(Z, (uint8_t*)Sa, nullptr, cnt + 2,
                                             256, 16384);
  gemm_l4<<<250, 256, 0, stream>>>(Sa, Wt4, Z);
  cuba_kernel<true><<<35, 64, 0, stream>>>(Z, nullptr, out, cnt + 3, 35, 2240);
  finalize_counts<<<1, 64, 0, stream>>>(cnt, out + 2240000);
}